// Round 8
// baseline (1252.559 us; speedup 1.0000x reference)
//
#include <hip/hip_runtime.h>
#include <math.h>

#define TT 1024
#define BB 16
#define CC 1024
#define HH 16
#define KK 7
#define PADL 6
#define HK 112          // H*K
#define LSTRIDE 116     // logits LDS row stride (floats)

typedef short bf16x8 __attribute__((ext_vector_type(8)));
typedef float f32x4 __attribute__((ext_vector_type(4)));

__device__ __forceinline__ short f2bf(float f) {
    union { float f; unsigned u; } v; v.f = f;
    unsigned r = v.u + 0x7fff + ((v.u >> 16) & 1);   // RNE; inputs finite
    return (short)(r >> 16);
}

// ---------------------------------------------------------------------------
// K0: W (112x1024 fp32) -> Wb (bf16). 114688 elems = 56 blocks x 256 thr x 8.
// ---------------------------------------------------------------------------
__global__ __launch_bounds__(256) void k0_cvtW(const float* __restrict__ W,
                                               short* __restrict__ Wb) {
    const int i = (blockIdx.x * 256 + threadIdx.x) * 8;
    const float4 a0 = *(const float4*)(W + i);
    const float4 a1 = *(const float4*)(W + i + 4);
    bf16x8 v;
    v[0] = f2bf(a0.x); v[1] = f2bf(a0.y); v[2] = f2bf(a0.z); v[3] = f2bf(a0.w);
    v[4] = f2bf(a1.x); v[5] = f2bf(a1.y); v[6] = f2bf(a1.z); v[7] = f2bf(a1.w);
    *(bf16x8*)(Wb + i) = v;
}

// ---------------------------------------------------------------------------
// KA (R8): k1 (MFMA logits+softmax -> wsm) FUSED with the dense zero-stream.
// Blocks 0..255: verbatim k1 (strip = blk*4+w). Blocks 256..2047 (1792):
// device-linear grid-stride nt zeroing of dense (1.07 GB) — consecutive
// threads write consecutive 16 B device-wide, the exact fillBufferAligned
// access shape. k1-blocks are FIRST in the grid so the initial residency
// (2 blocks/CU, LDS-limited) pairs one k1-block with one zero-block per CU:
// k1's serial ~80-150 us of compute hides entirely under the write drain.
// This is also the first confound-free test of fill-shaped in-kernel
// writes (R4 kept 2048 streams; R6's slab test was corrupted by its
// restructured low-occupancy k3 phase).
// ---------------------------------------------------------------------------
__global__ __launch_bounds__(256) void kA(const float* __restrict__ x,
                                          const short* __restrict__ Wb,
                                          float* __restrict__ wsm,
                                          float* __restrict__ dense) {
    __shared__ __align__(16) float Llog[4][16 * LSTRIDE];
    __shared__ __align__(16) float Lout[4][16 * HK];

    const int blk = blockIdx.x;
    const int tid = threadIdx.x;

    if (blk >= 256) {
        // ---- zero path: fill-shaped device-linear nt sweep ----
        const size_t NF4 = (size_t)BB * HH * TT * TT / 4;    // 67108864
        const size_t stride = (size_t)1792 * 256;            // 458752 f32x4
        f32x4* __restrict__ p = (f32x4*)dense;
        const f32x4 z = (f32x4){0.f, 0.f, 0.f, 0.f};
        for (size_t i = (size_t)(blk - 256) * 256 + tid; i < NF4; i += stride)
            __builtin_nontemporal_store(z, p + i);
        return;
    }

    // ---- k1 path (verbatim) ----
    const int w = tid >> 6;
    const int lane = tid & 63;
    const int quad = lane >> 4;
    const int lr = lane & 15;
    const int strip = blk * 4 + w;            // = t
    const int r0 = strip * 16;                // flat (t*B+b) row base

    // layout probe
    bf16x8 ap, bp;
#pragma unroll
    for (int e = 0; e < 8; ++e) {
        const int k = quad * 8 + e;
        ap[e] = (k == lr) ? (short)0x3F80 : (short)0;   // A = I (first 16 k)
        bp[e] = f2bf((float)k);                          // B[k][n] = k
    }
    f32x4 pz = (f32x4){0.f, 0.f, 0.f, 0.f};
    pz = __builtin_amdgcn_mfma_f32_16x16x32_bf16(ap, bp, pz, 0, 0, 0);
    const bool claim = (pz[0] == (float)(quad * 4)) &&
                       (pz[1] == (float)(quad * 4 + 1));

    // main GEMM
    const float* __restrict__ xa = x + (size_t)(r0 + lr) * CC + quad * 8;
    const short* __restrict__ wb = Wb + (size_t)lr * CC + quad * 8;

    f32x4 acc[7];
#pragma unroll
    for (int j = 0; j < 7; ++j) acc[j] = (f32x4){0.f, 0.f, 0.f, 0.f};

#pragma unroll 4
    for (int k0 = 0; k0 < CC; k0 += 32) {
        const float4 a0 = *(const float4*)(xa + k0);
        const float4 a1 = *(const float4*)(xa + k0 + 4);
        bf16x8 af;
        af[0] = f2bf(a0.x); af[1] = f2bf(a0.y); af[2] = f2bf(a0.z); af[3] = f2bf(a0.w);
        af[4] = f2bf(a1.x); af[5] = f2bf(a1.y); af[6] = f2bf(a1.z); af[7] = f2bf(a1.w);
#pragma unroll
        for (int j = 0; j < 7; ++j) {
            const bf16x8 bfrag = *(const bf16x8*)(wb + (size_t)(j * 16) * CC + k0);
            acc[j] = __builtin_amdgcn_mfma_f32_16x16x32_bf16(af, bfrag, acc[j], 0, 0, 0);
        }
    }

    // scatter D into LDS with runtime-selected mapping
#pragma unroll
    for (int j = 0; j < 7; ++j)
#pragma unroll
        for (int r = 0; r < 4; ++r) {
            const int rowi = claim ? (quad * 4 + r) : lr;
            const int coli = claim ? lr : (quad * 4 + r);
            Llog[w][rowi * LSTRIDE + j * 16 + coli] = acc[j][r];
        }
    __syncthreads();

    // masked softmax: 256 (row,head) pairs per wave, 4 per lane
    const int kmin = (strip >= PADL) ? 0 : (PADL - strip);
#pragma unroll
    for (int p = 0; p < 4; ++p) {
        const int idx = p * 64 + lane;        // 0..255
        const int m = idx >> 4;
        const int h = idx & 15;
        const float* lp = &Llog[w][m * LSTRIDE + h * KK];
        float a[KK];
#pragma unroll
        for (int k = 0; k < KK; ++k) a[k] = lp[k];

        float mx = -INFINITY;
#pragma unroll
        for (int k = 0; k < KK; ++k)
            if (k >= kmin) mx = fmaxf(mx, a[k]);
        float e[KK], s = 0.f;
#pragma unroll
        for (int k = 0; k < KK; ++k) {
            if (k >= kmin) { e[k] = expf(a[k] - mx); s += e[k]; }
            else           { e[k] = 0.f; }
        }
        const float inv = 1.f / s;
        float* op = &Lout[w][m * HK + h * KK];
#pragma unroll
        for (int k = 0; k < KK; ++k) op[k] = e[k] * inv;
    }
    __syncthreads();

    // coalesced copy-out: 1792 contiguous floats -> wsm + r0*112
    float* __restrict__ dst = wsm + (size_t)r0 * HK;
    const float* __restrict__ src = &Lout[w][0];
#pragma unroll
    for (int i = 0; i < 7; ++i) {
        const int o = i * 256 + lane * 4;
        *(float4*)(dst + o) = *(const float4*)(src + o);
    }
}

// ---------------------------------------------------------------------------
// KB (R8): band scatter (R7-verified) fused with k3 (R7-verified), 7:4
// interleave so scatter's 33 MB RMW writes overlap k3's x-reads.
// grid = 11264 = 1024*11; blk%11<4 -> k3 item, else scatter item.
// scatter: one thread per (t,b,h,j); coalesced wsm reads; writes 28 B
// contiguous per (bh,t) row into the pre-zeroed dense.
// k3: out[t,b,c] = sum_k wsm[t,b,h,k] * x[t+k-6,b,c], h = c/64.
// ---------------------------------------------------------------------------
__global__ __launch_bounds__(256) void kB(const float* __restrict__ x,
                                          const float* __restrict__ wsm,
                                          float* __restrict__ dense,
                                          float* __restrict__ out) {
    const int blk = blockIdx.x;
    const int r = blk % 11;
    const int q = blk / 11;

    if (r < 4) {
        // ---- k3 item ----
        const int item = q * 4 + r;           // 0..4095
        const int r0 = item << 2;
        const int t = r0 >> 4;
        const int c = threadIdx.x << 2;
        const int h = c >> 6;
        const int kmin = (t >= PADL) ? 0 : (PADL - t);

#pragma unroll
        for (int i = 0; i < 4; ++i) {
            const int row = r0 + i;
            const float* __restrict__ wp = wsm + ((size_t)row * HH + h) * KK;
            float w[KK];
#pragma unroll
            for (int k = 0; k < KK; ++k) w[k] = wp[k];

            f32x4 acc = (f32x4){0.f, 0.f, 0.f, 0.f};
            for (int k = kmin; k < KK; ++k) {
                const f32x4 xv = *(const f32x4*)(
                    x + ((size_t)row + (size_t)(k - PADL) * BB) * CC + c);
                acc[0] += w[k] * xv[0];
                acc[1] += w[k] * xv[1];
                acc[2] += w[k] * xv[2];
                acc[3] += w[k] * xv[3];
            }
            __builtin_nontemporal_store(acc,
                (f32x4*)(out + (size_t)row * CC + c));
        }
    } else {
        // ---- scatter item ----
        const int item = q * 7 + (r - 4);     // 0..7167
        const int idx = item * 256 + threadIdx.x;   // 0..1835007
        const float v = wsm[idx];

        const int j = idx % KK;
        const int rem = idx / KK;          // (t*16 + b)*16 + h
        const int h = rem & 15;
        const int rem2 = rem >> 4;         // t*16 + b
        const int b = rem2 & 15;
        const int t = rem2 >> 4;

        const int cc = t + j - PADL;
        if (cc >= 0) {
            const int bh = b * HH + h;
            dense[((size_t)bh * TT + t) * TT + cc] = v;
        }
    }
}

extern "C" void kernel_launch(void* const* d_in, const int* in_sizes, int n_in,
                              void* d_out, int out_size, void* d_ws, size_t ws_size,
                              hipStream_t stream) {
    const float* x = (const float*)d_in[0];   // (T, B, C)
    const float* W = (const float*)d_in[1];   // (H*K, C)
    float* out = (float*)d_out;                         // (T, B, C)
    float* dense = out + (size_t)TT * BB * CC;          // (B*H, T, T)
    float* wsm = (float*)d_ws;                          // (T, B, H, K)
    short* Wb = (short*)(wsm + (size_t)TT * BB * HK);   // bf16 W, 229 KB

    k0_cvtW<<<56, 256, 0, stream>>>(W, Wb);
    kA<<<2048, 256, 0, stream>>>(x, Wb, wsm, dense);
    kB<<<11264, 256, 0, stream>>>(x, wsm, dense, out);
}

// Round 10
// 1216.326 us; speedup vs baseline: 1.0298x; 1.0298x over previous
//
#include <hip/hip_runtime.h>
#include <math.h>

#define TT 1024
#define BB 16
#define CC 1024
#define HH 16
#define KK 7
#define PADL 6
#define HK 112          // H*K
#define LSTRIDE 116     // logits LDS row stride (floats)

typedef short bf16x8 __attribute__((ext_vector_type(8)));
typedef float f32x4 __attribute__((ext_vector_type(4)));

__device__ __forceinline__ short f2bf(float f) {
    union { float f; unsigned u; } v; v.f = f;
    unsigned r = v.u + 0x7fff + ((v.u >> 16) & 1);   // RNE; inputs finite
    return (short)(r >> 16);
}

// ---------------------------------------------------------------------------
// K0: W (112x1024 fp32) -> Wb (bf16). 114688 elems = 56 blocks x 256 thr x 8.
// ---------------------------------------------------------------------------
__global__ __launch_bounds__(256) void k0_cvtW(const float* __restrict__ W,
                                               short* __restrict__ Wb) {
    const int i = (blockIdx.x * 256 + threadIdx.x) * 8;
    const float4 a0 = *(const float4*)(W + i);
    const float4 a1 = *(const float4*)(W + i + 4);
    bf16x8 v;
    v[0] = f2bf(a0.x); v[1] = f2bf(a0.y); v[2] = f2bf(a0.z); v[3] = f2bf(a0.w);
    v[4] = f2bf(a1.x); v[5] = f2bf(a1.y); v[6] = f2bf(a1.z); v[7] = f2bf(a1.w);
    *(bf16x8*)(Wb + i) = v;
}

// ---------------------------------------------------------------------------
// KA (R9 resubmit): k1 (MFMA logits+softmax -> wsm, blocks 0..255, verbatim)
// fused with a PLAIN-STORE device-linear zero sweep of dense (blocks
// 256..2047). The 2x2 {policy}x{shape} audit: nt+tile (R3) ~2.9 TB/s,
// nt+linear (R6/R8) ~2.9, plain+tile (R5) ~2.8 (L2 thrash) — plain+linear
// is the untested cell and is exactly fillBufferAligned's shape (6.27 TB/s
// measured). Theory: nt bypasses L2's line/burst aggregation (half-rate to
// HBM); plain streams through L2 at full rate when the live footprint is
// small (linear sweep ~1 MB). Single variable vs R8's kA: nt -> plain.
// R8 already proved the k1/zero overlap works (kA = max, not sum).
// ---------------------------------------------------------------------------
__global__ __launch_bounds__(256) void kA(const float* __restrict__ x,
                                          const short* __restrict__ Wb,
                                          float* __restrict__ wsm,
                                          float* __restrict__ dense) {
    __shared__ __align__(16) float Llog[4][16 * LSTRIDE];
    __shared__ __align__(16) float Lout[4][16 * HK];

    const int blk = blockIdx.x;
    const int tid = threadIdx.x;

    if (blk >= 256) {
        // ---- zero path: device-linear sweep, PLAIN stores (the variable) ----
        const size_t NF4 = (size_t)BB * HH * TT * TT / 4;    // 67108864
        const size_t stride = (size_t)1792 * 256;            // 458752 f32x4
        f32x4* __restrict__ p = (f32x4*)dense;
        const f32x4 z = (f32x4){0.f, 0.f, 0.f, 0.f};
        for (size_t i = (size_t)(blk - 256) * 256 + tid; i < NF4; i += stride)
            p[i] = z;
        return;
    }

    // ---- k1 path (verbatim) ----
    const int w = tid >> 6;
    const int lane = tid & 63;
    const int quad = lane >> 4;
    const int lr = lane & 15;
    const int strip = blk * 4 + w;            // = t
    const int r0 = strip * 16;                // flat (t*B+b) row base

    // layout probe
    bf16x8 ap, bp;
#pragma unroll
    for (int e = 0; e < 8; ++e) {
        const int k = quad * 8 + e;
        ap[e] = (k == lr) ? (short)0x3F80 : (short)0;   // A = I (first 16 k)
        bp[e] = f2bf((float)k);                          // B[k][n] = k
    }
    f32x4 pz = (f32x4){0.f, 0.f, 0.f, 0.f};
    pz = __builtin_amdgcn_mfma_f32_16x16x32_bf16(ap, bp, pz, 0, 0, 0);
    const bool claim = (pz[0] == (float)(quad * 4)) &&
                       (pz[1] == (float)(quad * 4 + 1));

    // main GEMM
    const float* __restrict__ xa = x + (size_t)(r0 + lr) * CC + quad * 8;
    const short* __restrict__ wb = Wb + (size_t)lr * CC + quad * 8;

    f32x4 acc[7];
#pragma unroll
    for (int j = 0; j < 7; ++j) acc[j] = (f32x4){0.f, 0.f, 0.f, 0.f};

#pragma unroll 4
    for (int k0 = 0; k0 < CC; k0 += 32) {
        const float4 a0 = *(const float4*)(xa + k0);
        const float4 a1 = *(const float4*)(xa + k0 + 4);
        bf16x8 af;
        af[0] = f2bf(a0.x); af[1] = f2bf(a0.y); af[2] = f2bf(a0.z); af[3] = f2bf(a0.w);
        af[4] = f2bf(a1.x); af[5] = f2bf(a1.y); af[6] = f2bf(a1.z); af[7] = f2bf(a1.w);
#pragma unroll
        for (int j = 0; j < 7; ++j) {
            const bf16x8 bfrag = *(const bf16x8*)(wb + (size_t)(j * 16) * CC + k0);
            acc[j] = __builtin_amdgcn_mfma_f32_16x16x32_bf16(af, bfrag, acc[j], 0, 0, 0);
        }
    }

    // scatter D into LDS with runtime-selected mapping
#pragma unroll
    for (int j = 0; j < 7; ++j)
#pragma unroll
        for (int r = 0; r < 4; ++r) {
            const int rowi = claim ? (quad * 4 + r) : lr;
            const int coli = claim ? lr : (quad * 4 + r);
            Llog[w][rowi * LSTRIDE + j * 16 + coli] = acc[j][r];
        }
    __syncthreads();

    // masked softmax: 256 (row,head) pairs per wave, 4 per lane
    const int kmin = (strip >= PADL) ? 0 : (PADL - strip);
#pragma unroll
    for (int p = 0; p < 4; ++p) {
        const int idx = p * 64 + lane;        // 0..255
        const int m = idx >> 4;
        const int h = idx & 15;
        const float* lp = &Llog[w][m * LSTRIDE + h * KK];
        float a[KK];
#pragma unroll
        for (int k = 0; k < KK; ++k) a[k] = lp[k];

        float mx = -INFINITY;
#pragma unroll
        for (int k = 0; k < KK; ++k)
            if (k >= kmin) mx = fmaxf(mx, a[k]);
        float e[KK], s = 0.f;
#pragma unroll
        for (int k = 0; k < KK; ++k) {
            if (k >= kmin) { e[k] = expf(a[k] - mx); s += e[k]; }
            else           { e[k] = 0.f; }
        }
        const float inv = 1.f / s;
        float* op = &Lout[w][m * HK + h * KK];
#pragma unroll
        for (int k = 0; k < KK; ++k) op[k] = e[k] * inv;
    }
    __syncthreads();

    // coalesced copy-out: 1792 contiguous floats -> wsm + r0*112
    float* __restrict__ dst = wsm + (size_t)r0 * HK;
    const float* __restrict__ src = &Lout[w][0];
#pragma unroll
    for (int i = 0; i < 7; ++i) {
        const int o = i * 256 + lane * 4;
        *(float4*)(dst + o) = *(const float4*)(src + o);
    }
}

// ---------------------------------------------------------------------------
// KB (R9 resubmit): band-LINE writer fused with k3 (1:4, R3's proven
// interleave). Unlike R7/R8's scalar scatter (partial-line RMW into cold
// lines, ~+110us), each (bh,t) row's TWO aligned 128-B lines containing the
// band (64 floats starting at col S*32, S = max(0,t-6)>>5) are written
// FULLY (band values + zeros) by 16 threads x float4 — full-line writes,
// no RMW reads; they overwrite kA's zeros there (+67 MB double-write, no
// coordination; kA/kB are stream-ordered). Stores with col0 >= 1024 are
// skipped (no spill into the next row/bh). Band values via R3's proven
// 112-thread LDS gather. k3 part verbatim (nt out stores).
// grid = 20480: blk%5==0 -> k3 item (4096), else line-writer tile (16384).
// ---------------------------------------------------------------------------
__global__ __launch_bounds__(256) void kB(const float* __restrict__ x,
                                          const float* __restrict__ wsm,
                                          float* __restrict__ dense,
                                          float* __restrict__ out) {
    __shared__ float Lband[16][8];   // 512 B; line-writer path only
    const int blk = blockIdx.x;

    if ((blk % 5) == 0) {
        // ---- k3 item: out[t,b,c] = sum_k wsm[t,b,h,k] * x[t+k-6,b,c] ----
        const int r0 = (blk / 5) << 2;        // 4 flat rows, same t
        const int t = r0 >> 4;
        const int c = threadIdx.x << 2;
        const int h = c >> 6;
        const int kmin = (t >= PADL) ? 0 : (PADL - t);

#pragma unroll
        for (int i = 0; i < 4; ++i) {
            const int row = r0 + i;
            const float* __restrict__ wp = wsm + ((size_t)row * HH + h) * KK;
            float w[KK];
#pragma unroll
            for (int k = 0; k < KK; ++k) w[k] = wp[k];

            f32x4 acc = (f32x4){0.f, 0.f, 0.f, 0.f};
            for (int k = kmin; k < KK; ++k) {
                const f32x4 xv = *(const f32x4*)(
                    x + ((size_t)row + (size_t)(k - PADL) * BB) * CC + c);
                acc[0] += w[k] * xv[0];
                acc[1] += w[k] * xv[1];
                acc[2] += w[k] * xv[2];
                acc[3] += w[k] * xv[3];
            }
            __builtin_nontemporal_store(acc,
                (f32x4*)(out + (size_t)row * CC + c));
        }
    } else {
        // ---- band-line writer: tile (bh, t0..t0+15) ----
        const int blk2 = blk - (blk / 5) - 1;  // 0..16383
        const int bh = blk2 >> 6;
        const int tc = blk2 & 63;
        const int b = bh >> 4;
        const int h = bh & 15;
        const int t0 = tc * 16;
        const int tid = threadIdx.x;

        // band gather -> LDS (112 threads, one float each; R3-proven)
        if (tid < 112) {
            const int r = tid & 15;            // row within tile
            const int j = tid >> 4;            // tap 0..6
            Lband[r][j] =
                wsm[(((size_t)(t0 + r) * BB + b) * HH + h) * KK + j];
        }
        __syncthreads();

        // 16 threads per row write the 64-float line pair containing the band
        const int r = tid >> 4;                // row 0..15
        const int thrj = tid & 15;             // 0..15
        const int t = t0 + r;
        const int lo = t - PADL;
        const int S = (t >= PADL) ? ((t - PADL) >> 5) : 0;
        const int col0 = S * 32 + thrj * 4;

        if (col0 < TT) {
            f32x4 v;
#pragma unroll
            for (int l = 0; l < 4; ++l) {
                const int col = col0 + l;
                v[l] = (col >= lo && col <= t && col >= 0)
                           ? Lband[r][col - lo] : 0.f;
            }
            *(f32x4*)(dense + ((size_t)bh * TT + t) * TT + col0) = v;
        }
    }
}

extern "C" void kernel_launch(void* const* d_in, const int* in_sizes, int n_in,
                              void* d_out, int out_size, void* d_ws, size_t ws_size,
                              hipStream_t stream) {
    const float* x = (const float*)d_in[0];   // (T, B, C)
    const float* W = (const float*)d_in[1];   // (H*K, C)
    float* out = (float*)d_out;                         // (T, B, C)
    float* dense = out + (size_t)TT * BB * CC;          // (B*H, T, T)
    float* wsm = (float*)d_ws;                          // (T, B, H, K)
    short* Wb = (short*)(wsm + (size_t)TT * BB * HK);   // bf16 W, 229 KB

    k0_cvtW<<<56, 256, 0, stream>>>(W, Wb);
    kA<<<2048, 256, 0, stream>>>(x, Wb, wsm, dense);
    kB<<<5 * (TT * BB) / 4, 256, 0, stream>>>(x, wsm, dense, out);
}